// Round 3
// baseline (470.583 us; speedup 1.0000x reference)
//
#include <hip/hip_runtime.h>
#include <hip/hip_bf16.h>

// Problem: x:(4096,8,1024) f32, U:(8,1048576,4) f32, V:(4,1048576,4) f32,
// scale:(8,1), biasq:(8,1), bias:(8,1024) -> out:(4096,8,1024) f32
// D1=D2=1024, B=4096, N=8, K=4, BW=4, T=1.0

typedef __attribute__((ext_vector_type(8))) short short8;
typedef __attribute__((ext_vector_type(4))) float f32x4;
typedef __attribute__((ext_vector_type(4))) unsigned short ushort4v;
typedef __attribute__((ext_vector_type(2))) unsigned int uint2v;

__device__ __forceinline__ unsigned short f2bf(float f) {
  union { float f; unsigned u; } a; a.f = f;
  unsigned u = a.u;
  u += 0x7fffu + ((u >> 16) & 1u);   // RNE; inputs finite
  return (unsigned short)(u >> 16);
}

__device__ __forceinline__ unsigned pk2(float a, float b) {
  __hip_bfloat162 h = __float22bfloat162_rn(make_float2(a, b));
  union { __hip_bfloat162 h; unsigned u; } c; c.h = h;
  return c.u;
}

// ---------------------------------------------------------------------------
// Kernel 1 (merged prep): blocks [0,1024) = wgen, [1024,3072) = xcast.
// Overlaps wgen's transcendental VALU with xcast's pure streaming; one launch.
// ---------------------------------------------------------------------------
__global__ __launch_bounds__(256) void prep_kernel(
    const float4* __restrict__ U4, const float4* __restrict__ V4,
    const float* __restrict__ scale, const float* __restrict__ biasq,
    unsigned short* __restrict__ Wt,
    const float4* __restrict__ X4, uint2v* __restrict__ Xb) {
  __shared__ float tiles[8][32][33];
  const int bid = blockIdx.x;
  const int t = threadIdx.x;
  if (bid < 1024) {
    // ---- wgen: Theta -> sigmoid -> bit-weighted integer -> dequant -> Wt^T
    const int d1_0 = (bid & 31) * 32;
    const int d2_0 = (bid >> 5) * 32;
#pragma unroll
    for (int i = 0; i < 4; i++) {
      const int e = t + 256 * i;
      const int r = e >> 5, c = e & 31;        // r: d1 offset, c: d2 offset
      const size_t d = (size_t)(d1_0 + r) * 1024 + (size_t)(d2_0 + c);
      float4 u[8];
#pragma unroll
      for (int nn = 0; nn < 8; nn++) u[nn] = U4[((size_t)nn << 20) + d];
      float integ[8];
#pragma unroll
      for (int nn = 0; nn < 8; nn++) integ[nn] = 0.f;
#pragma unroll
      for (int b = 0; b < 4; b++) {
        const float4 v = V4[((size_t)b << 20) + d];
        const float pw = (float)(1 << b);
#pragma unroll
        for (int nn = 0; nn < 8; nn++) {
          float th = u[nn].x * v.x + u[nn].y * v.y + u[nn].z * v.z + u[nn].w * v.w;
          th = fminf(10.f, fmaxf(-10.f, th));
          integ[nn] += pw * __builtin_amdgcn_rcpf(1.f + __expf(-th));
        }
      }
#pragma unroll
      for (int nn = 0; nn < 8; nn++) tiles[nn][r][c] = integ[nn];
    }
    __syncthreads();
    const int orow = t >> 3;                   // d2 offset 0..31
    const int oc0 = (t & 7) * 4;               // d1 offset (x4)
#pragma unroll
    for (int nn = 0; nn < 8; nn++) {
      const float sc = scale[nn], bq = biasq[nn];
      ushort4v o;
      o.x = f2bf(sc * (tiles[nn][oc0 + 0][orow] - bq - 16.f));
      o.y = f2bf(sc * (tiles[nn][oc0 + 1][orow] - bq - 16.f));
      o.z = f2bf(sc * (tiles[nn][oc0 + 2][orow] - bq - 16.f));
      o.w = f2bf(sc * (tiles[nn][oc0 + 3][orow] - bq - 16.f));
      *(ushort4v*)(Wt + ((size_t)nn << 20) + (size_t)(d2_0 + orow) * 1024 +
                   (size_t)(d1_0 + oc0)) = o;
    }
  } else {
    // ---- xcast: X fp32 -> Xb bf16 (same layout), pure streaming
    const size_t total = (size_t)4096 * 8 * 1024 / 4;   // 8388608 float4s
    const size_t stride = (size_t)2048 * 256;
    for (size_t i = (size_t)(bid - 1024) * 256 + t; i < total; i += stride) {
      const float4 v = X4[i];
      uint2v p;
      p.x = pk2(v.x, v.y);
      p.y = pk2(v.z, v.w);
      Xb[i] = p;
    }
  }
}

// ---------------------------------------------------------------------------
// Kernel 2: batched bf16 GEMM — 256x256 8-phase schedule (T2+T3+T4+T5).
// 8 waves (2M x 4N, INTERLEAVED frag placement so phase quadrant (mq,nq)
// touches exactly LDS half (A:mq, B:nq) for every wave). BK=64, dbuf LDS
// 128 KiB. st_16x32 swizzle: LDS slot (row,chunk) holds global chunk
// chunk ^ (((row>>2)&1)<<1); applied by pre-swizzling the gload_lds SOURCE
// (LDS linear) and XOR-ing the ds_read chunk (both-sides involution).
// Staging: 1 half-tile/phase into the other dbuf, order A0,B0,B1,A1;
// counted waits vmcnt(4)/(4)/(4)/none per tile (derived; never 0 in loop),
// tail peeled with 4/2/0. setprio(1) around each 16-MFMA cluster.
// Grid lin = n + 8*(bn + 4*bm): member n pinned to XCD n (Wt panel
// L2-resident), bn-sharers of an x-panel adjacent in dispatch.
// ---------------------------------------------------------------------------
#define AS1(p) ((const __attribute__((address_space(1))) void*)(p))
#define AS3(p) ((__attribute__((address_space(3))) void*)(p))

#define PHASE(mq, nq, STAGE)                                                   \
  {                                                                            \
    __builtin_amdgcn_s_barrier();                                              \
    __builtin_amdgcn_sched_barrier(0);                                         \
    short8 af[4][2], bfv[2][2];                                                \
    _Pragma("unroll")                                                          \
    for (int mf2 = 0; mf2 < 4; mf2++)                                          \
      _Pragma("unroll")                                                        \
      for (int ks = 0; ks < 2; ks++)                                           \
        af[mf2][ks] = *(const short8*)(aRd + db16 + (mq) * 8192 +              \
                                       mf2 * 2048 + ks * 32 + cq8);            \
    _Pragma("unroll")                                                          \
    for (int nf2 = 0; nf2 < 2; nf2++)                                          \
      _Pragma("unroll")                                                        \
      for (int ks = 0; ks < 2; ks++)                                           \
        bfv[nf2][ks] = *(const short8*)(bRd + db16 + (nq) * 8192 +             \
                                        nf2 * 4096 + ks * 32 + cq8);           \
    STAGE;                                                                     \
    __builtin_amdgcn_s_setprio(1);                                             \
    _Pragma("unroll")                                                          \
    for (int ks = 0; ks < 2; ks++)                                             \
      _Pragma("unroll")                                                        \
      for (int mf2 = 0; mf2 < 4; mf2++)                                        \
        _Pragma("unroll")                                                      \
        for (int nf2 = 0; nf2 < 2; nf2++)                                      \
          acc[(mq) * 4 + mf2][(nq) * 2 + nf2] =                                \
              __builtin_amdgcn_mfma_f32_16x16x32_bf16(                         \
                  af[mf2][ks], bfv[nf2][ks],                                   \
                  acc[(mq) * 4 + mf2][(nq) * 2 + nf2], 0, 0, 0);               \
    __builtin_amdgcn_s_setprio(0);                                             \
  }

__global__ __launch_bounds__(512, 2) void gemm_kernel(
    const unsigned short* __restrict__ Xb,   // [4096][8][1024] bf16
    const unsigned short* __restrict__ Wt,   // [8][1024(l)][1024(d1)] bf16
    const float* __restrict__ bias,          // [8][1024]
    float* __restrict__ out) {               // [4096][8][1024]
  __shared__ unsigned short As[2 * 256 * 64];  // 64 KiB (2 dbuf x 2 half x 128x64)
  __shared__ unsigned short Bs[2 * 256 * 64];  // 64 KiB
  const int t = threadIdx.x;
  const int w = t >> 6;            // wave 0..7
  const int ln = t & 63;
  const int wm = w >> 2;           // 0..1  M interleave
  const int wn = w & 3;            // 0..3  N interleave

  const int lin = blockIdx.x;      // lin = n + 8*(bn + 4*bm)
  const int n   = lin & 7;
  const int bn0 = ((lin >> 3) & 3) * 256;
  const int bm0 = (lin >> 5) * 256;

  // ---- staging source: lane -> row_local = ln>>3, LDS chunk = ln&7;
  // pre-swizzled global chunk = (ln&7) ^ (((ln>>5)&1)<<1)  [key == row bit2]
  const int s_r = ln >> 3;
  const int s_c = (ln & 7) ^ (((ln >> 5) & 1) << 1);
  const unsigned short* aB =
      Xb + ((size_t)(bm0 + w * 16 + s_r) * 8 + n) * 1024 + s_c * 8;
  const unsigned short* bB =
      Wt + ((size_t)n << 20) + (size_t)(bn0 + w * 16 + s_r) * 1024 + s_c * 8;
  unsigned short* aL = As + w * 1024;          // wave-uniform LDS base
  unsigned short* bL = Bs + w * 1024;

  auto stageA = [&](int dbuf, int h, int kt) {
#pragma unroll
    for (int l = 0; l < 2; l++)
      __builtin_amdgcn_global_load_lds(
          AS1(aB + (size_t)h * 1048576 + (size_t)l * 65536 + kt * 64),
          AS3(aL + dbuf * 16384 + h * 8192 + l * 512), 16, 0, 0);
  };
  auto stageB = [&](int dbuf, int h, int kt) {
#pragma unroll
    for (int l = 0; l < 2; l++)
      __builtin_amdgcn_global_load_lds(
          AS1(bB + (size_t)h * 131072 + (size_t)l * 8192 + kt * 64),
          AS3(bL + dbuf * 16384 + h * 8192 + l * 512), 16, 0, 0);
  };

  // ---- fragment-read geometry
  const int lm = ln & 15;
  const int kq = ln >> 4;                        // chunk sub-index 0..3
  const int cq8 = (kq ^ (((lm >> 2) & 1) << 1)) * 8;  // swizzled chunk offset
  const unsigned short* aRd = As + (wm * 16 + lm) * 64;
  const unsigned short* bRd = Bs + (wn * 16 + lm) * 64;

  f32x4 acc[8][4];
#pragma unroll
  for (int i = 0; i < 8; i++)
#pragma unroll
    for (int j = 0; j < 4; j++) acc[i][j] = (f32x4){0.f, 0.f, 0.f, 0.f};

  // ---- prologue: stage tile 0 (A0, B0, B1, A1)
  stageA(0, 0, 0); stageB(0, 0, 0); stageB(0, 1, 0); stageA(0, 1, 0);

  // ---- steady state: tiles 0..14, staging tile kt+1 into the other dbuf
  for (int kt = 0; kt < 15; kt++) {
    const int db16 = (kt & 1) * 16384;
    const int nb = (kt & 1) ^ 1;
    const int nkt = kt + 1;
    asm volatile("s_waitcnt vmcnt(4)" ::: "memory");
    PHASE(0, 0, stageA(nb, 0, nkt));
    asm volatile("s_waitcnt vmcnt(4)" ::: "memory");
    PHASE(0, 1, stageB(nb, 0, nkt));
    asm volatile("s_waitcnt vmcnt(4)" ::: "memory");
    PHASE(1, 0, stageB(nb, 1, nkt));
    PHASE(1, 1, stageA(nb, 1, nkt));
  }
  // ---- tail: tile 15, no staging, drain 4 -> 2 -> 0
  {
    const int db16 = 16384;
    asm volatile("s_waitcnt vmcnt(4)" ::: "memory");
    PHASE(0, 0, (void)0);
    asm volatile("s_waitcnt vmcnt(2)" ::: "memory");
    PHASE(0, 1, (void)0);
    asm volatile("s_waitcnt vmcnt(0)" ::: "memory");
    PHASE(1, 0, (void)0);
    PHASE(1, 1, (void)0);
  }

  // ---- epilogue. C/D: col=lane&15, row=(lane>>4)*4+reg [m89/m91].
  // Frag block maps (interleaved): f_m = (mf>>2)*8 + (mf&3)*2 + wm,
  // f_n = (nf>>1)*8 + (nf&1)*4 + wn  (16-wide blocks).
  const int q4 = ln >> 4;
  float bv[4];
#pragma unroll
  for (int nf = 0; nf < 4; nf++)
    bv[nf] = bias[n * 1024 + bn0 + (nf >> 1) * 128 + (nf & 1) * 64 + wn * 16 + lm];
#pragma unroll
  for (int mf = 0; mf < 8; mf++) {
    const int rowb = bm0 + (mf >> 2) * 128 + (mf & 3) * 32 + wm * 16 + q4 * 4;
#pragma unroll
    for (int r = 0; r < 4; r++) {
      float* op = out + ((size_t)(rowb + r) * 8 + n) * 1024;
#pragma unroll
      for (int nf = 0; nf < 4; nf++)
        op[bn0 + (nf >> 1) * 128 + (nf & 1) * 64 + wn * 16 + lm] =
            acc[mf][nf][r] + bv[nf];
    }
  }
}

// ---------------------------------------------------------------------------
extern "C" void kernel_launch(void* const* d_in, const int* in_sizes, int n_in,
                              void* d_out, int out_size, void* d_ws, size_t ws_size,
                              hipStream_t stream) {
  const float* x     = (const float*)d_in[0];
  const float* U     = (const float*)d_in[1];
  const float* V     = (const float*)d_in[2];
  const float* scale = (const float*)d_in[3];
  const float* biasq = (const float*)d_in[4];
  const float* bias  = (const float*)d_in[5];
  float* out = (float*)d_out;

  // workspace: Wt bf16 [8][1024][1024] = 16 MiB, Xb bf16 [4096][8][1024] = 64 MiB
  unsigned short* Wt = (unsigned short*)d_ws;
  unsigned short* Xb = (unsigned short*)d_ws + (size_t)8 * 1024 * 1024;

  prep_kernel<<<dim3(3072), 256, 0, stream>>>((const float4*)U, (const float4*)V,
                                              scale, biasq, Wt,
                                              (const float4*)x, (uint2v*)Xb);
  gemm_kernel<<<dim3(512), 512, 0, stream>>>(Xb, Wt, bias, out);
}

// Round 4
// 449.242 us; speedup vs baseline: 1.0475x; 1.0475x over previous
//
#include <hip/hip_runtime.h>
#include <hip/hip_bf16.h>

// Problem: x:(4096,8,1024) f32, U:(8,1048576,4) f32, V:(4,1048576,4) f32,
// scale:(8,1), biasq:(8,1), bias:(8,1024) -> out:(4096,8,1024) f32
// D1=D2=1024, B=4096, N=8, K=4, BW=4, T=1.0

typedef __attribute__((ext_vector_type(8))) short short8;
typedef __attribute__((ext_vector_type(4))) float f32x4;
typedef __attribute__((ext_vector_type(4))) unsigned short ushort4v;
typedef __attribute__((ext_vector_type(2))) unsigned int uint2v;

__device__ __forceinline__ unsigned short f2bf(float f) {
  union { float f; unsigned u; } a; a.f = f;
  unsigned u = a.u;
  u += 0x7fffu + ((u >> 16) & 1u);   // RNE; inputs finite
  return (unsigned short)(u >> 16);
}

__device__ __forceinline__ unsigned pk2(float a, float b) {
  __hip_bfloat162 h = __float22bfloat162_rn(make_float2(a, b));
  union { __hip_bfloat162 h; unsigned u; } c; c.h = h;
  return c.u;
}

// ---------------------------------------------------------------------------
// Kernel 1 (merged prep): blocks [0,1024) = wgen, [1024,3072) = xcast.
// R4: LDS tile now holds FINAL bf16 (scale/biasq applied in phase 1).
// LDS 33.8KB -> 16.9KB => 8 blocks/CU (was 4) => occupancy 40% -> ~100%,
// which is the latency-hiding prep needed (BW was 1.9 TB/s, VALU 10%).
// scale/biasq are uniform loads -> SGPRs, no VGPR cost.
// ---------------------------------------------------------------------------
__global__ __launch_bounds__(256, 8) void prep_kernel(
    const float4* __restrict__ U4, const float4* __restrict__ V4,
    const float* __restrict__ scale, const float* __restrict__ biasq,
    unsigned short* __restrict__ Wt,
    const float4* __restrict__ X4, uint2v* __restrict__ Xb) {
  __shared__ unsigned short tiles[8][32][33];   // 16896 B
  const int bid = blockIdx.x;
  const int t = threadIdx.x;
  if (bid < 1024) {
    // ---- wgen: Theta -> sigmoid -> bit-weighted integer -> dequant -> Wt^T
    const int d1_0 = (bid & 31) * 32;
    const int d2_0 = (bid >> 5) * 32;
    float sc[8], bq[8];
#pragma unroll
    for (int nn = 0; nn < 8; nn++) {            // uniform -> s_load/SGPR
      sc[nn] = scale[nn];
      bq[nn] = biasq[nn];
    }
#pragma unroll
    for (int i = 0; i < 4; i++) {
      const int e = t + 256 * i;
      const int r = e >> 5, c = e & 31;        // r: d1 offset, c: d2 offset
      const size_t d = (size_t)(d1_0 + r) * 1024 + (size_t)(d2_0 + c);
      float4 u[8];
#pragma unroll
      for (int nn = 0; nn < 8; nn++) u[nn] = U4[((size_t)nn << 20) + d];
      float integ[8];
#pragma unroll
      for (int nn = 0; nn < 8; nn++) integ[nn] = 0.f;
#pragma unroll
      for (int b = 0; b < 4; b++) {
        const float4 v = V4[((size_t)b << 20) + d];
        const float pw = (float)(1 << b);
#pragma unroll
        for (int nn = 0; nn < 8; nn++) {
          float th = u[nn].x * v.x + u[nn].y * v.y + u[nn].z * v.z + u[nn].w * v.w;
          th = fminf(10.f, fmaxf(-10.f, th));
          integ[nn] += pw * __builtin_amdgcn_rcpf(1.f + __expf(-th));
        }
      }
#pragma unroll
      for (int nn = 0; nn < 8; nn++)
        tiles[nn][r][c] = f2bf(sc[nn] * (integ[nn] - bq[nn] - 16.f));
    }
    __syncthreads();
    const int orow = t >> 3;                   // d2 offset 0..31
    const int oc0 = (t & 7) * 4;               // d1 offset (x4)
#pragma unroll
    for (int nn = 0; nn < 8; nn++) {
      ushort4v o;
      o.x = tiles[nn][oc0 + 0][orow];
      o.y = tiles[nn][oc0 + 1][orow];
      o.z = tiles[nn][oc0 + 2][orow];
      o.w = tiles[nn][oc0 + 3][orow];
      *(ushort4v*)(Wt + ((size_t)nn << 20) + (size_t)(d2_0 + orow) * 1024 +
                   (size_t)(d1_0 + oc0)) = o;
    }
  } else {
    // ---- xcast: X fp32 -> Xb bf16 (same layout), pure streaming
    const size_t total = (size_t)4096 * 8 * 1024 / 4;   // 8388608 float4s
    const size_t stride = (size_t)2048 * 256;
    for (size_t i = (size_t)(bid - 1024) * 256 + t; i < total; i += stride) {
      const float4 v = X4[i];
      uint2v p;
      p.x = pk2(v.x, v.y);
      p.y = pk2(v.z, v.w);
      Xb[i] = p;
    }
  }
}

// ---------------------------------------------------------------------------
// Kernel 2: batched bf16 GEMM — 256x256 8-phase schedule (T2+T3+T4+T5).
// R4 change: phase order (0,0)->(0,1)->(1,1)->(1,0) with PERSISTENT
// fragments: A-frags reloaded only on mq change, B-frags only on nq change.
// ds_read_b128 per tile per wave: 48 -> 28 (-42% LDS issue pressure; the
// phase body was LDS-issue-oversubscribed ~2x vs its MFMA cluster).
// vmcnt schedule (re-derived for this order, staging A0,B0,B1,A1 per tile):
// vmcnt(4) before ph1/ph2/ph3, none before ph4; tail drains 4/2/0. Same
// swizzle (chunk ^ row-bit2 involution on both sides), same epilogue.
// ---------------------------------------------------------------------------
#define AS1(p) ((const __attribute__((address_space(1))) void*)(p))
#define AS3(p) ((__attribute__((address_space(3))) void*)(p))

#define LOAD_A(mq)                                                             \
  _Pragma("unroll")                                                            \
  for (int mf2 = 0; mf2 < 4; mf2++)                                            \
    _Pragma("unroll")                                                          \
    for (int ks = 0; ks < 2; ks++)                                             \
      af[mf2][ks] = *(const short8*)(aRd + db16 + (mq) * 8192 + mf2 * 2048 +   \
                                     ks * 32 + cq8);

#define LOAD_B(nq)                                                             \
  _Pragma("unroll")                                                            \
  for (int nf2 = 0; nf2 < 2; nf2++)                                            \
    _Pragma("unroll")                                                          \
    for (int ks = 0; ks < 2; ks++)                                             \
      bfr[nf2][ks] = *(const short8*)(bRd + db16 + (nq) * 8192 + nf2 * 4096 +  \
                                      ks * 32 + cq8);

#define MFMAS(mq, nq)                                                          \
  __builtin_amdgcn_s_setprio(1);                                               \
  _Pragma("unroll")                                                            \
  for (int ks = 0; ks < 2; ks++)                                               \
    _Pragma("unroll")                                                          \
    for (int mf2 = 0; mf2 < 4; mf2++)                                          \
      _Pragma("unroll")                                                        \
      for (int nf2 = 0; nf2 < 2; nf2++)                                        \
        acc[(mq) * 4 + mf2][(nq) * 2 + nf2] =                                  \
            __builtin_amdgcn_mfma_f32_16x16x32_bf16(                           \
                af[mf2][ks], bfr[nf2][ks],                                     \
                acc[(mq) * 4 + mf2][(nq) * 2 + nf2], 0, 0, 0);                 \
  __builtin_amdgcn_s_setprio(0);                                               \
  __builtin_amdgcn_sched_barrier(0);

#define PH_TOP()                                                               \
  __builtin_amdgcn_s_barrier();                                                \
  __builtin_amdgcn_sched_barrier(0);

__global__ __launch_bounds__(512, 2) void gemm_kernel(
    const unsigned short* __restrict__ Xb,   // [4096][8][1024] bf16
    const unsigned short* __restrict__ Wt,   // [8][1024(l)][1024(d1)] bf16
    const float* __restrict__ bias,          // [8][1024]
    float* __restrict__ out) {               // [4096][8][1024]
  __shared__ unsigned short As[2 * 256 * 64];  // 64 KiB
  __shared__ unsigned short Bs[2 * 256 * 64];  // 64 KiB
  const int t = threadIdx.x;
  const int w = t >> 6;            // wave 0..7
  const int ln = t & 63;
  const int wm = w >> 2;           // 0..1  M interleave
  const int wn = w & 3;            // 0..3  N interleave

  const int lin = blockIdx.x;      // lin = n + 8*(bn + 4*bm)
  const int n   = lin & 7;
  const int bn0 = ((lin >> 3) & 3) * 256;
  const int bm0 = (lin >> 5) * 256;

  // ---- staging source: lane -> row_local = ln>>3, LDS chunk = ln&7;
  // pre-swizzled global chunk = (ln&7) ^ (((ln>>5)&1)<<1)  [key == row bit2]
  const int s_r = ln >> 3;
  const int s_c = (ln & 7) ^ (((ln >> 5) & 1) << 1);
  const unsigned short* aB =
      Xb + ((size_t)(bm0 + w * 16 + s_r) * 8 + n) * 1024 + s_c * 8;
  const unsigned short* bB =
      Wt + ((size_t)n << 20) + (size_t)(bn0 + w * 16 + s_r) * 1024 + s_c * 8;
  unsigned short* aL = As + w * 1024;          // wave-uniform LDS base
  unsigned short* bL = Bs + w * 1024;

  auto stageA = [&](int dbuf, int h, int kt) {
#pragma unroll
    for (int l = 0; l < 2; l++)
      __builtin_amdgcn_global_load_lds(
          AS1(aB + (size_t)h * 1048576 + (size_t)l * 65536 + kt * 64),
          AS3(aL + dbuf * 16384 + h * 8192 + l * 512), 16, 0, 0);
  };
  auto stageB = [&](int dbuf, int h, int kt) {
#pragma unroll
    for (int l = 0; l < 2; l++)
      __builtin_amdgcn_global_load_lds(
          AS1(bB + (size_t)h * 131072 + (size_t)l * 8192 + kt * 64),
          AS3(bL + dbuf * 16384 + h * 8192 + l * 512), 16, 0, 0);
  };

  // ---- fragment-read geometry
  const int lm = ln & 15;
  const int kq = ln >> 4;                        // chunk sub-index 0..3
  const int cq8 = (kq ^ (((lm >> 2) & 1) << 1)) * 8;  // swizzled chunk offset
  const unsigned short* aRd = As + (wm * 16 + lm) * 64;
  const unsigned short* bRd = Bs + (wn * 16 + lm) * 64;

  f32x4 acc[8][4];
#pragma unroll
  for (int i = 0; i < 8; i++)
#pragma unroll
    for (int j = 0; j < 4; j++) acc[i][j] = (f32x4){0.f, 0.f, 0.f, 0.f};

  short8 af[4][2], bfr[2][2];

  // ---- prologue: stage tile 0 (A0, B0, B1, A1)
  stageA(0, 0, 0); stageB(0, 0, 0); stageB(0, 1, 0); stageA(0, 1, 0);

  // ---- steady state: tiles 0..14, staging tile kt+1 into the other dbuf
  for (int kt = 0; kt < 15; kt++) {
    const int db16 = (kt & 1) * 16384;
    const int nb = (kt & 1) ^ 1;
    const int nkt = kt + 1;
    asm volatile("s_waitcnt vmcnt(4)" ::: "memory");
    PH_TOP();
    LOAD_A(0) LOAD_B(0)
    stageA(nb, 0, nkt);
    MFMAS(0, 0)
    asm volatile("s_waitcnt vmcnt(4)" ::: "memory");
    PH_TOP();
    LOAD_B(1)
    stageB(nb, 0, nkt);
    MFMAS(0, 1)
    asm volatile("s_waitcnt vmcnt(4)" ::: "memory");
    PH_TOP();
    LOAD_A(1)
    stageB(nb, 1, nkt);
    MFMAS(1, 1)
    PH_TOP();
    LOAD_B(0)
    stageA(nb, 1, nkt);
    MFMAS(1, 0)
  }
  // ---- tail: tile 15 (dbuf 1), no staging, drain 4 -> 2 -> 0
  {
    const int db16 = 16384;
    asm volatile("s_waitcnt vmcnt(4)" ::: "memory");
    PH_TOP();
    LOAD_A(0) LOAD_B(0)
    MFMAS(0, 0)
    asm volatile("s_waitcnt vmcnt(2)" ::: "memory");
    PH_TOP();
    LOAD_B(1)
    MFMAS(0, 1)
    asm volatile("s_waitcnt vmcnt(0)" ::: "memory");
    PH_TOP();
    LOAD_A(1)
    MFMAS(1, 1)
    PH_TOP();
    LOAD_B(0)
    MFMAS(1, 0)
  }

  // ---- epilogue. C/D: col=lane&15, row=(lane>>4)*4+reg [m89/m91].
  // Frag maps (interleaved): row = bm0+(mf>>2)*128+(mf&3)*32+wm*16+q4*4+r,
  // col = bn0+(nf>>1)*128+(nf&1)*64+wn*16+lm.
  const int q4 = ln >> 4;
  float bv[4];
#pragma unroll
  for (int nf = 0; nf < 4; nf++)
    bv[nf] = bias[n * 1024 + bn0 + (nf >> 1) * 128 + (nf & 1) * 64 + wn * 16 + lm];
#pragma unroll
  for (int mf = 0; mf < 8; mf++) {
    const int rowb = bm0 + (mf >> 2) * 128 + (mf & 3) * 32 + wm * 16 + q4 * 4;
#pragma unroll
    for (int r = 0; r < 4; r++) {
      float* op = out + ((size_t)(rowb + r) * 8 + n) * 1024;
#pragma unroll
      for (int nf = 0; nf < 4; nf++)
        op[bn0 + (nf >> 1) * 128 + (nf & 1) * 64 + wn * 16 + lm] =
            acc[mf][nf][r] + bv[nf];
    }
  }
}

// ---------------------------------------------------------------------------
extern "C" void kernel_launch(void* const* d_in, const int* in_sizes, int n_in,
                              void* d_out, int out_size, void* d_ws, size_t ws_size,
                              hipStream_t stream) {
  const float* x     = (const float*)d_in[0];
  const float* U     = (const float*)d_in[1];
  const float* V     = (const float*)d_in[2];
  const float* scale = (const float*)d_in[3];
  const float* biasq = (const float*)d_in[4];
  const float* bias  = (const float*)d_in[5];
  float* out = (float*)d_out;

  // workspace: Wt bf16 [8][1024][1024] = 16 MiB, Xb bf16 [4096][8][1024] = 64 MiB
  unsigned short* Wt = (unsigned short*)d_ws;
  unsigned short* Xb = (unsigned short*)d_ws + (size_t)8 * 1024 * 1024;

  prep_kernel<<<dim3(3072), 256, 0, stream>>>((const float4*)U, (const float4*)V,
                                              scale, biasq, Wt,
                                              (const float4*)x, (uint2v*)Xb);
  gemm_kernel<<<dim3(512), 512, 0, stream>>>(Xb, Wt, bias, out);
}